// Round 1
// baseline (202.022 us; speedup 1.0000x reference)
//
#include <hip/hip_runtime.h>
#include <math.h>

// Problem: B=16384, D=512, R=64, E=8.
// out = x0 * (sum_e g_e * (x @ V[e]^T C[e] U[e]^T)) + g@b + x*sum(g)
// Folded: VC[n=e*64+s][d] = sum_r V[e,r,d] C[e,r,s]  ->  xvc = x @ VC^T (GEMM1)
//         Ut[d][n=e*64+s] = U[e,d,s]                  ->  gproj = (g.xvc) @ Ut^T (GEMM2)
//
// R3 (fused): one kernel per 64-row slab does GEMM1 -> gate-scale -> T in LDS
//             -> GEMM2 -> epilogue. T never touches HBM (-32MB). B tiles (VCc/Ut,
//             512KB each, L2-resident) double-buffered with counted vmcnt(2) +
//             raw s_barrier so prefetch stays in flight across barriers.
// LDS: A-slab 64KB + T-slab 64KB + B dbuf 16KB = 144KB -> 1 block/CU, 256 blocks.

typedef __bf16 bf16_t;
typedef __attribute__((ext_vector_type(8))) __bf16 bf16x8;
typedef __attribute__((ext_vector_type(4))) __bf16 bf16x4;
typedef __attribute__((ext_vector_type(4))) float  floatx4;

// async 16B/lane global->LDS (LDS dest = wave-uniform base + lane*16)
__device__ __forceinline__ void async16(void* lds, const void* gp) {
  __builtin_amdgcn_global_load_lds(
      (__attribute__((address_space(1))) void*)(gp),
      (__attribute__((address_space(3))) void*)(lds), 16, 0, 0);
}

// ---------------- K0: weight prep (unchanged, verified) --------------------
__global__ __launch_bounds__(256) void prep_kernel(
    const float* __restrict__ U, const float* __restrict__ V, const float* __restrict__ C,
    bf16_t* __restrict__ VCc, bf16_t* __restrict__ Ut) {
  int tid = blockIdx.x * 256 + threadIdx.x;
  if (tid < 512 * 512) {
    int n = tid >> 9, d = tid & 511;
    int e = n >> 6, s = n & 63;
    const float* Vp = V + (size_t)e * 64 * 512 + d;
    const float* Cp = C + (size_t)e * 64 * 64 + s;
    float acc = 0.f;
#pragma unroll 8
    for (int r = 0; r < 64; ++r) acc += Vp[(size_t)r * 512] * Cp[r * 64];
    VCc[tid] = (bf16_t)acc;
  } else {
    int i2 = tid - 512 * 512;
    int d = i2 >> 9, n = i2 & 511;
    int e = n >> 6, s = n & 63;
    Ut[i2] = (bf16_t)U[((size_t)e * 512 + d) * 64 + s];
  }
}

// ---------------- K1: x -> bf16 cast + gate softmax (unchanged, verified) --
__global__ __launch_bounds__(256) void gate_kernel(
    const float* __restrict__ x, const float* __restrict__ Wg, const float* __restrict__ bg,
    bf16_t* __restrict__ xbf, float* __restrict__ g) {
  int wave = threadIdx.x >> 6, lane = threadIdx.x & 63;
  int row = blockIdx.x * 4 + wave;
  const float4* xr = (const float4*)(x + (size_t)row * 512);
  float4 v0 = xr[lane];
  float4 v1 = xr[lane + 64];
  bf16x4* xb = (bf16x4*)(xbf + (size_t)row * 512);
  bf16x4 b0, b1;
  b0.x = (bf16_t)v0.x; b0.y = (bf16_t)v0.y; b0.z = (bf16_t)v0.z; b0.w = (bf16_t)v0.w;
  b1.x = (bf16_t)v1.x; b1.y = (bf16_t)v1.y; b1.z = (bf16_t)v1.z; b1.w = (bf16_t)v1.w;
  xb[lane] = b0;
  xb[lane + 64] = b1;
  float acc[8];
#pragma unroll
  for (int e = 0; e < 8; ++e) {
    const float4* wp = (const float4*)(Wg + (size_t)e * 512);
    float4 w0 = wp[lane], w1 = wp[lane + 64];
    acc[e] = v0.x * w0.x + v0.y * w0.y + v0.z * w0.z + v0.w * w0.w +
             v1.x * w1.x + v1.y * w1.y + v1.z * w1.z + v1.w * w1.w;
  }
#pragma unroll
  for (int e = 0; e < 8; ++e) {
#pragma unroll
    for (int off = 32; off > 0; off >>= 1) acc[e] += __shfl_xor(acc[e], off, 64);
  }
  float z[8], mx = -1e30f;
#pragma unroll
  for (int e = 0; e < 8; ++e) { z[e] = acc[e] + bg[e]; mx = fmaxf(mx, z[e]); }
  float s = 0.f;
#pragma unroll
  for (int e = 0; e < 8; ++e) { z[e] = __expf(z[e] - mx); s += z[e]; }
  float inv = 1.f / s;
  if (lane == 0) {
#pragma unroll
    for (int e = 0; e < 8; ++e) g[(size_t)row * 8 + e] = z[e] * inv;
  }
}

// ---------------- K2: fused GEMM1 -> T(LDS) -> GEMM2 -> epilogue -----------
// Flat loop: it in [0,128). phase=it>>6 (0: A=xbf-slab,B=VCc -> T; 1: A=T,B=Ut -> out)
// nc=(it>>3)&7 is 64-col output chunk (== expert for phase 0), kt=it&7 is K-step.
// Per iter: stage B tile for it+1 into buf[(it+1)&1]; vmcnt(2) keeps those 2
// loads in flight while guaranteeing buf[it&1] is complete; 2 raw barriers.
// Swizzle (both slabs + B tiles): 16B chunk slot q of row r holds global chunk
// q^(r&7) within each 8-chunk (128B) group -> ds_read_b128 frags 2-way = free.
__global__ __launch_bounds__(256, 1) void fused_kernel(
    const bf16_t* __restrict__ xbf, const bf16_t* __restrict__ VCc,
    const bf16_t* __restrict__ Ut, const float* __restrict__ g,
    const float* __restrict__ bvec, const float* __restrict__ x0,
    const float* __restrict__ x, float* __restrict__ out) {
  __shared__ alignas(16) char lds[147456];
  char* ldsA = lds;              // [64 rows][1024B] xbf slab (swizzled)
  char* ldsT = lds + 65536;      // [64 rows][1024B] T slab (swizzled)
  char* ldsB = lds + 131072;     // 2 x 8KB B tiles [64 n][128B]
  const int t = threadIdx.x;
  const int wave = t >> 6, lane = t & 63;
  const int wr = wave >> 1, wc = wave & 1;       // 2x2 waves, wave-tile 32x32
  const int lhi = lane >> 4, llo = lane & 15;
  const int m0 = blockIdx.x * 64;

  // ---- prologue: stage B tile for it=0 (VCc nc=0,kt=0), preload A slab ----
#pragma unroll
  for (int i = 0; i < 2; ++i) {
    int c = i * 256 + t, r = c >> 3, q = c & 7, p = q ^ (r & 7);
    async16(ldsB + (i * 256 + wave * 64) * 16,
            (const char*)VCc + (size_t)r * 1024 + p * 16);
  }
#pragma unroll
  for (int i = 0; i < 16; ++i) {                 // 64 rows x 1024B = 4096 chunks
    int c = i * 256 + t;
    int r = c >> 6, cc = c & 63, grp = cc >> 3, q = cc & 7, p = q ^ (r & 7);
    async16(ldsA + (i * 256 + wave * 64) * 16,
            (const char*)xbf + (size_t)(m0 + r) * 1024 + grp * 128 + p * 16);
  }

  floatx4 acc[2][2];
#pragma unroll 1
  for (int it = 0; it < 128; ++it) {
    const int phase = it >> 6, nc = (it >> 3) & 7, kt = it & 7;
    const int bsel = it & 1;
    if (it < 127) {
      const int nx = it + 1;
      const int pnc = (nx >> 3) & 7, pkt = nx & 7;
      const char* src = (const char*)((nx >> 6) ? Ut : VCc);
#pragma unroll
      for (int i = 0; i < 2; ++i) {
        int c = i * 256 + t, r = c >> 3, q = c & 7, p = q ^ (r & 7);
        async16(ldsB + ((nx & 1) * 512 + i * 256 + wave * 64) * 16,
                src + (size_t)(pnc * 64 + r) * 1024 + pkt * 128 + p * 16);
      }
      asm volatile("s_waitcnt vmcnt(2)" ::: "memory");  // cur tile ready; 2 in flight
    } else {
      asm volatile("s_waitcnt vmcnt(0)" ::: "memory");
    }
    __builtin_amdgcn_s_barrier();                // all waves: buf[bsel] loaded
    if (kt == 0) {
#pragma unroll
      for (int i = 0; i < 2; ++i)
#pragma unroll
        for (int j = 0; j < 2; ++j) acc[i][j] = (floatx4){0.f, 0.f, 0.f, 0.f};
    }
    const char* Ab = phase ? ldsT : ldsA;
#pragma unroll
    for (int ks = 0; ks < 2; ++ks) {
      bf16x8 af[2], bfm[2];
#pragma unroll
      for (int i = 0; i < 2; ++i) {
        int rA = wr * 32 + i * 16 + llo;
        af[i] = *(const bf16x8*)(Ab + rA * 1024 + kt * 128 +
                                 (((ks * 4 + lhi) ^ (rA & 7)) << 4));
      }
#pragma unroll
      for (int j = 0; j < 2; ++j) {
        int rB = wc * 32 + j * 16 + llo;
        bfm[j] = *(const bf16x8*)(ldsB + bsel * 8192 + rB * 128 +
                                  (((ks * 4 + lhi) ^ (rB & 7)) << 4));
      }
#pragma unroll
      for (int i = 0; i < 2; ++i)
#pragma unroll
        for (int j = 0; j < 2; ++j)
          acc[i][j] = __builtin_amdgcn_mfma_f32_16x16x32_bf16(af[i], bfm[j], acc[i][j], 0, 0, 0);
    }
    if (kt == 7) {
      if (phase == 0) {
        // gate-scale (e = nc) and write T chunk into ldsT (swizzled, bf16)
#pragma unroll
        for (int i = 0; i < 2; ++i) {
#pragma unroll
          for (int r = 0; r < 4; ++r) {
            int ml = wr * 32 + i * 16 + lhi * 4 + r;   // C/D: col=lane&15, row=quad*4+reg
            float gv = g[(size_t)(m0 + ml) * 8 + nc];
#pragma unroll
            for (int j = 0; j < 2; ++j) {
              int n = nc * 64 + wc * 32 + j * 16 + llo;
              int cch = n >> 3;
              int slot = (cch & ~7) | ((cch & 7) ^ (ml & 7));
              *(bf16_t*)(ldsT + ml * 1024 + slot * 16 + (n & 7) * 2) =
                  (bf16_t)(acc[i][j][r] * gv);
            }
          }
        }
        asm volatile("s_waitcnt lgkmcnt(0)" ::: "memory");  // T writes visible pre-barrier
      } else {
        // final epilogue: out = x0*gproj + g@b + x*sum(g)
        float bb[2][8];
#pragma unroll
        for (int j = 0; j < 2; ++j) {
          int n = nc * 64 + wc * 32 + j * 16 + llo;
#pragma unroll
          for (int e = 0; e < 8; ++e) bb[j][e] = bvec[(size_t)e * 512 + n];
        }
#pragma unroll
        for (int i = 0; i < 2; ++i) {
#pragma unroll
          for (int r = 0; r < 4; ++r) {
            int m = m0 + wr * 32 + i * 16 + lhi * 4 + r;
            float g8[8], gsum = 0.f;
#pragma unroll
            for (int e = 0; e < 8; ++e) { g8[e] = g[(size_t)m * 8 + e]; gsum += g8[e]; }
#pragma unroll
            for (int j = 0; j < 2; ++j) {
              int n = nc * 64 + wc * 32 + j * 16 + llo;
              float bias = 0.f;
#pragma unroll
              for (int e = 0; e < 8; ++e) bias += g8[e] * bb[j][e];
              size_t idx = (size_t)m * 512 + n;
              out[idx] = x0[idx] * acc[i][j][r] + bias + x[idx] * gsum;
            }
          }
        }
      }
    }
    __builtin_amdgcn_s_barrier();                // buf[bsel] free for restage
  }
}

// ---------------- launch ----------------------------------------------------
extern "C" void kernel_launch(void* const* d_in, const int* in_sizes, int n_in,
                              void* d_out, int out_size, void* d_ws, size_t ws_size,
                              hipStream_t stream) {
  const float* x0 = (const float*)d_in[0];
  const float* x  = (const float*)d_in[1];
  const float* U  = (const float*)d_in[2];
  const float* V  = (const float*)d_in[3];
  const float* C  = (const float*)d_in[4];
  const float* bv = (const float*)d_in[5];
  const float* Wg = (const float*)d_in[6];
  const float* bg = (const float*)d_in[7];
  float* out = (float*)d_out;

  char* ws = (char*)d_ws;
  bf16_t* xbf = (bf16_t*)(ws);                               // 16,777,216 B
  bf16_t* VCc = (bf16_t*)(ws + 16777216);                    //    524,288 B
  bf16_t* Ut  = (bf16_t*)(ws + 17301504);                    //    524,288 B
  float*  g   = (float*)(ws + 17825792);                     //    524,288 B

  prep_kernel<<<2048, 256, 0, stream>>>(U, V, C, VCc, Ut);
  gate_kernel<<<4096, 256, 0, stream>>>(x, Wg, bg, xbf, g);
  fused_kernel<<<256, 256, 0, stream>>>(xbf, VCc, Ut, g, bv, x0, x, out);
}

// Round 2
// 201.155 us; speedup vs baseline: 1.0043x; 1.0043x over previous
//
#include <hip/hip_runtime.h>
#include <math.h>

// Problem: B=16384, D=512, R=64, E=8.
// out = x0 * (sum_e g_e * (x @ V[e]^T C[e] U[e]^T)) + g@b + x*sum(g)
// Folded: VCc[n=e*64+s][d] = sum_r V[e,r,d] C[e,r,s]  (Bt for GEMM1, K=d contig)
//         Ut [d][n=e*64+s] = U[e,d,s]                  (Bt for GEMM2, K=n contig)
//
// R4: latency-bound fix (R3: 7% Mfma, 10% occ, 256 barriers/block, 1 wave/SIMD).
//  - B read global->reg (L2-resident 1MB), pipelined 1 K-step ahead: no B LDS,
//    no manual vmcnt, no per-iter barriers. 2 barriers/block total.
//  - 64-row slab, 512 thr / 8 waves (2m x 4n, wave-tile 32x128), LDS 130KB:
//    1 block/CU but 2 waves/SIMD; L2 B-traffic halved vs 32-row blocks.
//  - prep+gate merged into one setup launch.

typedef __bf16 bf16_t;
typedef __attribute__((ext_vector_type(8))) __bf16 bf16x8;
typedef __attribute__((ext_vector_type(4))) __bf16 bf16x4;
typedef __attribute__((ext_vector_type(4))) float  floatx4;

// async 16B/lane global->LDS (LDS dest = wave-uniform base + lane*16)
__device__ __forceinline__ void async16(void* lds, const void* gp) {
  __builtin_amdgcn_global_load_lds(
      (__attribute__((address_space(1))) void*)(gp),
      (__attribute__((address_space(3))) void*)(lds), 16, 0, 0);
}

// ---------------- K0: setup = weight prep + (x->bf16 cast, gate softmax) ---
// blocks [0,2048): prep (verbatim-verified)  [2048,6144): gate (verbatim-verified)
__global__ __launch_bounds__(256) void setup_kernel(
    const float* __restrict__ U, const float* __restrict__ V, const float* __restrict__ C,
    const float* __restrict__ x, const float* __restrict__ Wg, const float* __restrict__ bg,
    bf16_t* __restrict__ VCc, bf16_t* __restrict__ Ut,
    bf16_t* __restrict__ xbf, float* __restrict__ g) {
  if (blockIdx.x < 2048) {
    int tid = blockIdx.x * 256 + threadIdx.x;
    if (tid < 512 * 512) {
      int n = tid >> 9, d = tid & 511;
      int e = n >> 6, s = n & 63;
      const float* Vp = V + (size_t)e * 64 * 512 + d;
      const float* Cp = C + (size_t)e * 64 * 64 + s;
      float acc = 0.f;
#pragma unroll 8
      for (int r = 0; r < 64; ++r) acc += Vp[(size_t)r * 512] * Cp[r * 64];
      VCc[tid] = (bf16_t)acc;
    } else {
      int i2 = tid - 512 * 512;
      int d = i2 >> 9, n = i2 & 511;
      int e = n >> 6, s = n & 63;
      Ut[i2] = (bf16_t)U[((size_t)e * 512 + d) * 64 + s];
    }
  } else {
    int wave = threadIdx.x >> 6, lane = threadIdx.x & 63;
    int row = (blockIdx.x - 2048) * 4 + wave;
    const float4* xr = (const float4*)(x + (size_t)row * 512);
    float4 v0 = xr[lane];
    float4 v1 = xr[lane + 64];
    bf16x4* xb = (bf16x4*)(xbf + (size_t)row * 512);
    bf16x4 b0, b1;
    b0.x = (bf16_t)v0.x; b0.y = (bf16_t)v0.y; b0.z = (bf16_t)v0.z; b0.w = (bf16_t)v0.w;
    b1.x = (bf16_t)v1.x; b1.y = (bf16_t)v1.y; b1.z = (bf16_t)v1.z; b1.w = (bf16_t)v1.w;
    xb[lane] = b0;
    xb[lane + 64] = b1;
    float acc[8];
#pragma unroll
    for (int e = 0; e < 8; ++e) {
      const float4* wp = (const float4*)(Wg + (size_t)e * 512);
      float4 w0 = wp[lane], w1 = wp[lane + 64];
      acc[e] = v0.x * w0.x + v0.y * w0.y + v0.z * w0.z + v0.w * w0.w +
               v1.x * w1.x + v1.y * w1.y + v1.z * w1.z + v1.w * w1.w;
    }
#pragma unroll
    for (int e = 0; e < 8; ++e) {
#pragma unroll
      for (int off = 32; off > 0; off >>= 1) acc[e] += __shfl_xor(acc[e], off, 64);
    }
    float z[8], mx = -1e30f;
#pragma unroll
    for (int e = 0; e < 8; ++e) { z[e] = acc[e] + bg[e]; mx = fmaxf(mx, z[e]); }
    float s = 0.f;
#pragma unroll
    for (int e = 0; e < 8; ++e) { z[e] = __expf(z[e] - mx); s += z[e]; }
    float inv = 1.f / s;
    if (lane == 0) {
#pragma unroll
      for (int e = 0; e < 8; ++e) g[(size_t)row * 8 + e] = z[e] * inv;
    }
  }
}

// ---------------- gemm half: M=64(slab) x N=512, K=512 --------------------
// A from LDS slab [64 rows][1024B], XOR-swizzled (chunk slot q of row r holds
// global chunk q^(r&7) within each 128B group). B from GLOBAL (Bt [outcol][K],
// 1KB rows, L2-resident), register double-buffered 1 K-step ahead.
// Wave (wr,wc): rows wr*32+[0,32), cols wc*128+[0,128). acc[2][8] floatx4.
__device__ __forceinline__ void gemm_half(
    const char* AB, const char* __restrict__ Bsrc,
    int wr, int wc, int llo, int lhi, floatx4 acc[2][8]) {
  const char* bp = Bsrc + (size_t)(wc * 128 + llo) * 1024 + lhi * 16;
  const int rA0 = wr * 32 + llo, rA1 = rA0 + 16;
  const char* ap0 = AB + rA0 * 1024;
  const char* ap1 = AB + rA1 * 1024;
  bf16x8 bc[8], bn[8], ac[2], an[2];
#pragma unroll
  for (int jj = 0; jj < 8; ++jj) bc[jj] = *(const bf16x8*)(bp + jj * 16384);
  ac[0] = *(const bf16x8*)(ap0 + ((lhi ^ (rA0 & 7)) << 4));
  ac[1] = *(const bf16x8*)(ap1 + ((lhi ^ (rA1 & 7)) << 4));
#pragma unroll 2
  for (int kt = 0; kt < 16; ++kt) {
    const int ktn = (kt + 1) & 15;
#pragma unroll
    for (int jj = 0; jj < 8; ++jj)
      bn[jj] = *(const bf16x8*)(bp + jj * 16384 + ktn * 64);
    {
      const int c = ktn * 4 + lhi;
      const int g0 = (c >> 3) * 128, sq = c & 7;
      an[0] = *(const bf16x8*)(ap0 + g0 + ((sq ^ (rA0 & 7)) << 4));
      an[1] = *(const bf16x8*)(ap1 + g0 + ((sq ^ (rA1 & 7)) << 4));
    }
#pragma unroll
    for (int jj = 0; jj < 8; ++jj)
      acc[0][jj] = __builtin_amdgcn_mfma_f32_16x16x32_bf16(ac[0], bc[jj], acc[0][jj], 0, 0, 0);
#pragma unroll
    for (int jj = 0; jj < 8; ++jj)
      acc[1][jj] = __builtin_amdgcn_mfma_f32_16x16x32_bf16(ac[1], bc[jj], acc[1][jj], 0, 0, 0);
    ac[0] = an[0]; ac[1] = an[1];
#pragma unroll
    for (int jj = 0; jj < 8; ++jj) bc[jj] = bn[jj];
  }
}

// ---------------- K1: fused GEMM1 -> T(LDS) -> GEMM2 -> epilogue -----------
__global__ __launch_bounds__(512, 2) void fused_kernel(
    const bf16_t* __restrict__ xbf, const bf16_t* __restrict__ VCc,
    const bf16_t* __restrict__ Ut, const float* __restrict__ g,
    const float* __restrict__ bvec, const float* __restrict__ x0,
    const float* __restrict__ x, float* __restrict__ out) {
  __shared__ alignas(16) char lds[133120];
  char* ldsA = lds;              // [64 rows][1024B] xbf slab (swizzled)
  char* ldsT = lds + 65536;      // [64 rows][1024B] T slab (swizzled)
  char* ldsG = lds + 131072;     // [64 rows][8 f32] gates
  const int t = threadIdx.x;
  const int wave = t >> 6, lane = t & 63;
  const int wr = wave >> 2, wc = wave & 3;   // 2m x 4n waves, wave-tile 32x128
  const int lhi = lane >> 4, llo = lane & 15;
  const int m0 = blockIdx.x * 64;

  // ---- prologue: g slab (512 f32) + A slab (64KB) via async16 ----
  if (t < 128)
    async16(ldsG + wave * 1024, (const char*)g + (size_t)m0 * 32 + t * 16);
#pragma unroll
  for (int i = 0; i < 8; ++i) {
    int c = i * 512 + t;
    int r = c >> 6, cc = c & 63, grp = cc >> 3, q = cc & 7, p = q ^ (r & 7);
    async16(ldsA + (i * 512 + wave * 64) * 16,
            (const char*)xbf + (size_t)(m0 + r) * 1024 + grp * 128 + p * 16);
  }
  __syncthreads();   // barrier 1 of 2 (drains vmcnt)

  // ---- phase 0: GEMM1 (A=xbf slab, B=VCc) ----
  floatx4 acc[2][8];
#pragma unroll
  for (int i = 0; i < 2; ++i)
#pragma unroll
    for (int jj = 0; jj < 8; ++jj) acc[i][jj] = (floatx4){0.f, 0.f, 0.f, 0.f};
  gemm_half(ldsA, (const char*)VCc, wr, wc, llo, lhi, acc);

  // ---- epilogue 0: gate-scale (expert = col/64) -> T slab (bf16, swizzled) ----
  float2 gv[2][4];   // g[m][wc*2], g[m][wc*2+1] for this lane's 8 rows
#pragma unroll
  for (int i = 0; i < 2; ++i)
#pragma unroll
    for (int r = 0; r < 4; ++r) {
      int ml = wr * 32 + i * 16 + lhi * 4 + r;
      gv[i][r] = *(const float2*)(ldsG + ml * 32 + wc * 8);
    }
#pragma unroll
  for (int i = 0; i < 2; ++i)
#pragma unroll
    for (int jj = 0; jj < 8; ++jj)
#pragma unroll
      for (int r = 0; r < 4; ++r) {
        int ml = wr * 32 + i * 16 + lhi * 4 + r;   // C/D: col=lane&15, row=quad*4+reg
        int n = wc * 128 + jj * 16 + llo;
        int cch = n >> 3;
        int slot = (cch & ~7) | ((cch & 7) ^ (ml & 7));
        float gvv = (jj >> 2) ? gv[i][r].y : gv[i][r].x;
        *(bf16_t*)(ldsT + ml * 1024 + slot * 16 + (n & 7) * 2) =
            (bf16_t)(acc[i][jj][r] * gvv);
      }
  __syncthreads();   // barrier 2 of 2 (drains lgkm: T visible)

  // ---- phase 1: GEMM2 (A=T slab, B=Ut) ----
#pragma unroll
  for (int i = 0; i < 2; ++i)
#pragma unroll
    for (int jj = 0; jj < 8; ++jj) acc[i][jj] = (floatx4){0.f, 0.f, 0.f, 0.f};
  gemm_half(ldsT, (const char*)Ut, wr, wc, llo, lhi, acc);

  // ---- epilogue 1: out = x0*gproj + g@b + x*sum(g) ----
  float bb[8][8];    // bvec[e][n] for this lane's 8 column positions
#pragma unroll
  for (int jj = 0; jj < 8; ++jj) {
    int n = wc * 128 + jj * 16 + llo;
#pragma unroll
    for (int e = 0; e < 8; ++e) bb[jj][e] = bvec[(size_t)e * 512 + n];
  }
#pragma unroll
  for (int i = 0; i < 2; ++i)
#pragma unroll
    for (int r = 0; r < 4; ++r) {
      int ml = wr * 32 + i * 16 + lhi * 4 + r;
      float4 ga = *(const float4*)(ldsG + ml * 32);
      float4 gb = *(const float4*)(ldsG + ml * 32 + 16);
      float g8[8] = {ga.x, ga.y, ga.z, ga.w, gb.x, gb.y, gb.z, gb.w};
      float gsum = ga.x + ga.y + ga.z + ga.w + gb.x + gb.y + gb.z + gb.w;
      size_t mrow = (size_t)(m0 + ml) * 512;
#pragma unroll
      for (int jj = 0; jj < 8; ++jj) {
        int n = wc * 128 + jj * 16 + llo;
        float bias = 0.f;
#pragma unroll
        for (int e = 0; e < 8; ++e) bias += g8[e] * bb[jj][e];
        size_t idx = mrow + n;
        out[idx] = x0[idx] * acc[i][jj][r] + bias + x[idx] * gsum;
      }
    }
}

// ---------------- launch ----------------------------------------------------
extern "C" void kernel_launch(void* const* d_in, const int* in_sizes, int n_in,
                              void* d_out, int out_size, void* d_ws, size_t ws_size,
                              hipStream_t stream) {
  const float* x0 = (const float*)d_in[0];
  const float* x  = (const float*)d_in[1];
  const float* U  = (const float*)d_in[2];
  const float* V  = (const float*)d_in[3];
  const float* C  = (const float*)d_in[4];
  const float* bv = (const float*)d_in[5];
  const float* Wg = (const float*)d_in[6];
  const float* bg = (const float*)d_in[7];
  float* out = (float*)d_out;

  char* ws = (char*)d_ws;
  bf16_t* xbf = (bf16_t*)(ws);                               // 16,777,216 B
  bf16_t* VCc = (bf16_t*)(ws + 16777216);                    //    524,288 B
  bf16_t* Ut  = (bf16_t*)(ws + 17301504);                    //    524,288 B
  float*  g   = (float*)(ws + 17825792);                     //    524,288 B

  setup_kernel<<<6144, 256, 0, stream>>>(U, V, C, x, Wg, bg, VCc, Ut, xbf, g);
  fused_kernel<<<256, 512, 0, stream>>>(xbf, VCc, Ut, g, bv, x0, x, out);
}

// Round 3
// 200.201 us; speedup vs baseline: 1.0091x; 1.0048x over previous
//
#include <hip/hip_runtime.h>
#include <math.h>

// Problem: B=16384, D=512, R=64, E=8.
// out = x0 * (sum_e g_e * (x @ V[e]^T C[e] U[e]^T)) + g@b + x*sum(g)
// Folded: VCc[n=e*64+s][d] = sum_r V[e,r,d] C[e,r,s]  (Bt for GEMM1, K=d contig)
//         Ut [d][n=e*64+s] = U[e,d,s]                  (Bt for GEMM2, K=n contig)
//
// R5: kill the ~110us setup half (R3/R4: total-fused ~= 110us both rounds).
//  - gate folded INTO fused (block owns 64 full rows; f32 dot + softmax in-wave).
//    xbf and g never touch HBM: x is cast to bf16 while staging the A-slab.
//  - prep rewritten LDS-tiled (C[e],V-slice staged once; no 64x L2 re-read).
//  - fused: 1024 thr = 16 waves (4/SIMD) for latency hiding; wave-tile 32x64
//    (2m x 8n => expert == wc); T-slab overwrites A-slab (dead after phase 0);
//    LDS 66KB; B streamed global->reg (L2-resident 1MB), depth-1 pipeline.

typedef __bf16 bf16_t;
typedef __attribute__((ext_vector_type(8))) __bf16 bf16x8;
typedef __attribute__((ext_vector_type(4))) float  floatx4;

// async 16B/lane global->LDS (LDS dest = wave-uniform base + lane*16)
__device__ __forceinline__ void async16(void* lds, const void* gp) {
  __builtin_amdgcn_global_load_lds(
      (__attribute__((address_space(1))) void*)(gp),
      (__attribute__((address_space(3))) void*)(lds), 16, 0, 0);
}

// ---------------- K0: weight prep, LDS-tiled --------------------------------
// blocks 0..63: VCc for (e = b>>3, d-block db = b&7).
//   stage C[e] 16KB + V[e][:,db*64..+64] 16KB once; 64-deep dot from LDS.
// blocks 64..127: Ut copy/cast (4096 elems per block, 16 per thread).
__global__ __launch_bounds__(256) void prep_kernel(
    const float* __restrict__ U, const float* __restrict__ V, const float* __restrict__ C,
    bf16_t* __restrict__ VCc, bf16_t* __restrict__ Ut) {
  const int b = blockIdx.x, t = threadIdx.x;
  if (b < 64) {
    __shared__ alignas(16) char ldsbuf[32768];
    float* ldsC = (float*)ldsbuf;            // [64 r][64 s]
    float* ldsV = (float*)(ldsbuf + 16384);  // [64 r][64 d]
    const int e = b >> 3, db = b & 7;
#pragma unroll
    for (int i = 0; i < 4; ++i) {            // C[e]: 1024 chunks of 16B
      int c = i * 256 + t;
      async16(ldsbuf + c * 16, (const char*)C + (size_t)e * 16384 + c * 16);
    }
#pragma unroll
    for (int i = 0; i < 4; ++i) {            // V[e][r][db*64..+64]
      int c = i * 256 + t, r = c >> 4, cc = c & 15;
      async16(ldsbuf + 16384 + c * 16,
              (const char*)V + (size_t)(e * 64 + r) * 2048 + db * 256 + cc * 16);
    }
    __syncthreads();
    const int s = t & 63, dg = t >> 6;       // thread: row n=e*64+s, cols dg*16..+16
    float acc16[16];
#pragma unroll
    for (int k = 0; k < 16; ++k) acc16[k] = 0.f;
#pragma unroll 4
    for (int r = 0; r < 64; ++r) {
      float cv = ldsC[r * 64 + s];
      floatx4 v[4];
#pragma unroll
      for (int j = 0; j < 4; ++j) v[j] = *(const floatx4*)(ldsV + r * 64 + dg * 16 + j * 4);
#pragma unroll
      for (int j = 0; j < 4; ++j)
#pragma unroll
        for (int k = 0; k < 4; ++k) acc16[j * 4 + k] = fmaf(v[j][k], cv, acc16[j * 4 + k]);
    }
    bf16_t* dst = VCc + (size_t)(e * 64 + s) * 512 + db * 64 + dg * 16;
    bf16x8 o0, o1;
#pragma unroll
    for (int k = 0; k < 8; ++k) { o0[k] = (bf16_t)acc16[k]; o1[k] = (bf16_t)acc16[8 + k]; }
    *(bf16x8*)dst = o0;
    *(bf16x8*)(dst + 8) = o1;
  } else {
    const int base = (b - 64) * 4096 + t * 16;       // Ut linear index
    const int d = base >> 9, n0 = base & 511;
    const int e = n0 >> 6, s0 = n0 & 63;
    const float* src = U + ((size_t)e * 512 + d) * 64 + s0;
    bf16x8 o0, o1;
#pragma unroll
    for (int k = 0; k < 8; ++k) { o0[k] = (bf16_t)src[k]; o1[k] = (bf16_t)src[8 + k]; }
    *(bf16x8*)(Ut + base) = o0;
    *(bf16x8*)(Ut + base + 8) = o1;
  }
}

// ---------------- gemm half: 64(slab) x 512, K=512, wave-tile 32x64 --------
// A from LDS slab [64 rows][1024B] bf16, XOR-swizzled (logical k-chunk sq of
// row r stored at slot sq^(r&7) within its 128B group). B from GLOBAL
// (Bt [outcol][K] 1KB rows, L2-resident), register-pipelined 1 K-step ahead.
__device__ __forceinline__ void gemm_half(
    const char* ap0, const char* ap1, const char* __restrict__ bp,
    int lhi, int rm, floatx4 acc[2][4]) {
  bf16x8 bc[4], bn[4], ac[2], an[2];
#pragma unroll
  for (int jj = 0; jj < 4; ++jj) bc[jj] = *(const bf16x8*)(bp + jj * 16384);
  ac[0] = *(const bf16x8*)(ap0 + ((lhi ^ rm) << 4));
  ac[1] = *(const bf16x8*)(ap1 + ((lhi ^ rm) << 4));
#pragma unroll 1
  for (int kt = 0; kt < 16; ++kt) {
    const int ktn = (kt + 1) & 15;
#pragma unroll
    for (int jj = 0; jj < 4; ++jj)
      bn[jj] = *(const bf16x8*)(bp + jj * 16384 + ktn * 64);
    const int c = ktn * 4 + lhi, g0 = (c >> 3) * 128, sq = c & 7;
    an[0] = *(const bf16x8*)(ap0 + g0 + ((sq ^ rm) << 4));
    an[1] = *(const bf16x8*)(ap1 + g0 + ((sq ^ rm) << 4));
#pragma unroll
    for (int jj = 0; jj < 4; ++jj)
      acc[0][jj] = __builtin_amdgcn_mfma_f32_16x16x32_bf16(ac[0], bc[jj], acc[0][jj], 0, 0, 0);
#pragma unroll
    for (int jj = 0; jj < 4; ++jj)
      acc[1][jj] = __builtin_amdgcn_mfma_f32_16x16x32_bf16(ac[1], bc[jj], acc[1][jj], 0, 0, 0);
    ac[0] = an[0]; ac[1] = an[1];
#pragma unroll
    for (int jj = 0; jj < 4; ++jj) bc[jj] = bn[jj];
  }
}

// ---------------- K1: gate + GEMM1 -> T(LDS) -> GEMM2 -> epilogue ----------
__global__ __launch_bounds__(1024, 4) void fused_kernel(
    const float* __restrict__ x0, const float* __restrict__ x,
    const bf16_t* __restrict__ VCc, const bf16_t* __restrict__ Ut,
    const float* __restrict__ Wg, const float* __restrict__ bg,
    const float* __restrict__ bvec, float* __restrict__ out) {
  __shared__ alignas(16) char lds[67584];
  char*  ldsX = lds;                     // [64][1024B] bf16 swizzled: x, then T
  float* ldsG = (float*)(lds + 65536);   // [64][8] gates
  const int t = threadIdx.x;
  const int wave = t >> 6, lane = t & 63;
  const int wr = wave >> 3, wc = wave & 7;   // 2m x 8n; cols wc*64 => expert==wc
  const int lhi = lane >> 4, llo = lane & 15;
  const int m0 = blockIdx.x * 64;

  // ---- stage x slab -> bf16 ldsX (swizzled): 4 chunks of 8 f32 per thread ----
  {
    const float4* xs = (const float4*)(x + (size_t)m0 * 512);
#pragma unroll
    for (int i = 0; i < 4; ++i) {
      int c = i * 1024 + t, r = c >> 6, q = c & 63;
      float4 f0 = xs[r * 128 + q * 2];
      float4 f1 = xs[r * 128 + q * 2 + 1];
      bf16x8 v;
      v[0] = (bf16_t)f0.x; v[1] = (bf16_t)f0.y; v[2] = (bf16_t)f0.z; v[3] = (bf16_t)f0.w;
      v[4] = (bf16_t)f1.x; v[5] = (bf16_t)f1.y; v[6] = (bf16_t)f1.z; v[7] = (bf16_t)f1.w;
      int slot = (q & 7) ^ (r & 7);
      *(bf16x8*)(ldsX + r * 1024 + (q >> 3) * 128 + slot * 16) = v;
    }
  }

  // ---- gate: wave handles rows wave*4+p; f32 dot + butterfly + softmax ----
#pragma unroll 1
  for (int p = 0; p < 4; ++p) {
    const int rl = wave * 4 + p;
    const float4* xr = (const float4*)(x + (size_t)(m0 + rl) * 512 + lane * 8);
    float4 xa = xr[0], xb = xr[1];
    float z[8];
#pragma unroll
    for (int e = 0; e < 8; ++e) {
      const float4* wp = (const float4*)(Wg + (size_t)e * 512 + lane * 8);
      float4 wa = wp[0], wb = wp[1];
      z[e] = xa.x * wa.x + xa.y * wa.y + xa.z * wa.z + xa.w * wa.w +
             xb.x * wb.x + xb.y * wb.y + xb.z * wb.z + xb.w * wb.w;
    }
#pragma unroll
    for (int e = 0; e < 8; ++e)
#pragma unroll
      for (int off = 32; off > 0; off >>= 1) z[e] += __shfl_xor(z[e], off, 64);
    if (lane == 0) {
      float mx = -1e30f, ssum = 0.f;
#pragma unroll
      for (int e = 0; e < 8; ++e) { z[e] += bg[e]; mx = fmaxf(mx, z[e]); }
#pragma unroll
      for (int e = 0; e < 8; ++e) { z[e] = __expf(z[e] - mx); ssum += z[e]; }
      float inv = 1.f / ssum;
      float4 ga = {z[0] * inv, z[1] * inv, z[2] * inv, z[3] * inv};
      float4 gb = {z[4] * inv, z[5] * inv, z[6] * inv, z[7] * inv};
      *(float4*)(ldsG + rl * 8) = ga;
      *(float4*)(ldsG + rl * 8 + 4) = gb;
    }
  }
  __syncthreads();   // ldsX staged + ldsG ready (drains vm+lgkm)

  // ---- phase 0: GEMM1 (A = x slab, B = VCc) ----
  const int rA0 = wr * 32 + llo, rA1 = rA0 + 16, rm = rA0 & 7;  // (rA0+16)&7 == rm
  const char* ap0 = ldsX + rA0 * 1024;
  const char* ap1 = ldsX + rA1 * 1024;
  const char* bp0 = (const char*)VCc + (size_t)(wc * 64 + llo) * 1024 + lhi * 16;
  floatx4 acc[2][4];
#pragma unroll
  for (int i = 0; i < 2; ++i)
#pragma unroll
    for (int jj = 0; jj < 4; ++jj) acc[i][jj] = (floatx4){0.f, 0.f, 0.f, 0.f};
  gemm_half(ap0, ap1, bp0, lhi, rm, acc);
  __syncthreads();   // all waves done reading x slab

  // ---- T = gate-scaled xvc, written over ldsX (bf16, same swizzle) ----
#pragma unroll
  for (int i = 0; i < 2; ++i)
#pragma unroll
    for (int r = 0; r < 4; ++r) {
      int ml = wr * 32 + i * 16 + lhi * 4 + r;   // C/D: col=lane&15, row=quad*4+reg
      float gv = ldsG[ml * 8 + wc];              // expert == wc
#pragma unroll
      for (int jj = 0; jj < 4; ++jj) {
        int n = wc * 64 + jj * 16 + llo;
        int q = n >> 3, slot = (q & 7) ^ (ml & 7);
        *(bf16_t*)(ldsX + ml * 1024 + (q >> 3) * 128 + slot * 16 + (n & 7) * 2) =
            (bf16_t)(acc[i][jj][r] * gv);
      }
    }
  __syncthreads();   // T visible (drains lgkm)

  // ---- phase 1: GEMM2 (A = T slab, B = Ut) ----
  const char* bp1 = (const char*)Ut + (size_t)(wc * 64 + llo) * 1024 + lhi * 16;
#pragma unroll
  for (int i = 0; i < 2; ++i)
#pragma unroll
    for (int jj = 0; jj < 4; ++jj) acc[i][jj] = (floatx4){0.f, 0.f, 0.f, 0.f};
  gemm_half(ap0, ap1, bp1, lhi, rm, acc);

  // ---- final epilogue: out = x0*gproj + g@b + x*sum(g) ----
  float bb[4][8];
#pragma unroll
  for (int jj = 0; jj < 4; ++jj) {
    int n = wc * 64 + jj * 16 + llo;
#pragma unroll
    for (int e = 0; e < 8; ++e) bb[jj][e] = bvec[(size_t)e * 512 + n];
  }
#pragma unroll
  for (int i = 0; i < 2; ++i)
#pragma unroll
    for (int r = 0; r < 4; ++r) {
      int ml = wr * 32 + i * 16 + lhi * 4 + r;
      float4 ga = *(const float4*)(ldsG + ml * 8);
      float4 gb = *(const float4*)(ldsG + ml * 8 + 4);
      float g8[8] = {ga.x, ga.y, ga.z, ga.w, gb.x, gb.y, gb.z, gb.w};
      float gsum = ga.x + ga.y + ga.z + ga.w + gb.x + gb.y + gb.z + gb.w;
      size_t mrow = (size_t)(m0 + ml) * 512;
#pragma unroll
      for (int jj = 0; jj < 4; ++jj) {
        int n = wc * 64 + jj * 16 + llo;
        float bias = 0.f;
#pragma unroll
        for (int e = 0; e < 8; ++e) bias += g8[e] * bb[jj][e];
        size_t idx = mrow + n;
        out[idx] = x0[idx] * acc[i][jj][r] + bias + x[idx] * gsum;
      }
    }
}

// ---------------- launch ----------------------------------------------------
extern "C" void kernel_launch(void* const* d_in, const int* in_sizes, int n_in,
                              void* d_out, int out_size, void* d_ws, size_t ws_size,
                              hipStream_t stream) {
  const float* x0 = (const float*)d_in[0];
  const float* x  = (const float*)d_in[1];
  const float* U  = (const float*)d_in[2];
  const float* V  = (const float*)d_in[3];
  const float* C  = (const float*)d_in[4];
  const float* bv = (const float*)d_in[5];
  const float* Wg = (const float*)d_in[6];
  const float* bg = (const float*)d_in[7];
  float* out = (float*)d_out;

  char* ws = (char*)d_ws;
  bf16_t* VCc = (bf16_t*)(ws);              // 524,288 B
  bf16_t* Ut  = (bf16_t*)(ws + 524288);     // 524,288 B

  prep_kernel<<<128, 256, 0, stream>>>(U, V, C, VCc, Ut);
  fused_kernel<<<256, 1024, 0, stream>>>(x0, x, VCc, Ut, Wg, bg, bv, out);
}

// Round 4
// 161.096 us; speedup vs baseline: 1.2540x; 1.2427x over previous
//
#include <hip/hip_runtime.h>
#include <math.h>

// Problem: B=16384, D=512, R=64, E=8.
// out = x0 * (sum_e g_e * (x @ V[e]^T C[e] U[e]^T)) + g@b + x*sum(g)
// Folded: VCc[n=e*64+s][d] = sum_r V[e,r,d] C[e,r,s]  (Bt for GEMM1, K=d contig)
//         Ut [d][n=e*64+s] = U[e,d,s]                  (Bt for GEMM2, K=n contig)
//
// R6: m97-style staging (R4/R5's global->reg B streaming made the compiler
// serialize/spill: VGPR 64-88 vs ~150 needed, 6% Mfma). Inner loop now has NO
// global loads: B staged [256n][64K]=32KB chunks via global_load_lds, dbuf,
// 16 barriers/phase, stage-next-then-compute (prefetch hides under MFMA).
// A-slab (x as bf16, swizzled) resident in LDS; T overwrites it between phases.
// 512 thr / 8 waves (2m x 4n), wave-tile 32x64, acc[2][8]. LDS 130KB, 1 blk/CU.
// ~90us of total is fixed harness reset dispatches (12 dispatches/iter).

typedef __bf16 bf16_t;
typedef __attribute__((ext_vector_type(8))) __bf16 bf16x8;
typedef __attribute__((ext_vector_type(4))) float  floatx4;

#define MFMA16 __builtin_amdgcn_mfma_f32_16x16x32_bf16

// async 16B/lane global->LDS (LDS dest = wave-uniform base + lane*16)
__device__ __forceinline__ void async16(void* lds, const void* gp) {
  __builtin_amdgcn_global_load_lds(
      (__attribute__((address_space(1))) void*)(gp),
      (__attribute__((address_space(3))) void*)(lds), 16, 0, 0);
}

// ---------------- K0: weight prep, LDS-tiled (verified R5) ------------------
__global__ __launch_bounds__(256) void prep_kernel(
    const float* __restrict__ U, const float* __restrict__ V, const float* __restrict__ C,
    bf16_t* __restrict__ VCc, bf16_t* __restrict__ Ut) {
  const int b = blockIdx.x, t = threadIdx.x;
  if (b < 64) {
    __shared__ alignas(16) char ldsbuf[32768];
    float* ldsC = (float*)ldsbuf;            // [64 r][64 s]
    float* ldsV = (float*)(ldsbuf + 16384);  // [64 r][64 d]
    const int e = b >> 3, db = b & 7;
#pragma unroll
    for (int i = 0; i < 4; ++i) {
      int c = i * 256 + t;
      async16(ldsbuf + c * 16, (const char*)C + (size_t)e * 16384 + c * 16);
    }
#pragma unroll
    for (int i = 0; i < 4; ++i) {
      int c = i * 256 + t, r = c >> 4, cc = c & 15;
      async16(ldsbuf + 16384 + c * 16,
              (const char*)V + (size_t)(e * 64 + r) * 2048 + db * 256 + cc * 16);
    }
    __syncthreads();
    const int s = t & 63, dg = t >> 6;
    float acc16[16];
#pragma unroll
    for (int k = 0; k < 16; ++k) acc16[k] = 0.f;
#pragma unroll 4
    for (int r = 0; r < 64; ++r) {
      float cv = ldsC[r * 64 + s];
      floatx4 v[4];
#pragma unroll
      for (int j = 0; j < 4; ++j) v[j] = *(const floatx4*)(ldsV + r * 64 + dg * 16 + j * 4);
#pragma unroll
      for (int j = 0; j < 4; ++j)
#pragma unroll
        for (int k = 0; k < 4; ++k) acc16[j * 4 + k] = fmaf(v[j][k], cv, acc16[j * 4 + k]);
    }
    bf16_t* dst = VCc + (size_t)(e * 64 + s) * 512 + db * 64 + dg * 16;
    bf16x8 o0, o1;
#pragma unroll
    for (int k = 0; k < 8; ++k) { o0[k] = (bf16_t)acc16[k]; o1[k] = (bf16_t)acc16[8 + k]; }
    *(bf16x8*)dst = o0;
    *(bf16x8*)(dst + 8) = o1;
  } else {
    const int base = (b - 64) * 4096 + t * 16;
    const int d = base >> 9, n0 = base & 511;
    const int e = n0 >> 6, s0 = n0 & 63;
    const float* src = U + ((size_t)e * 512 + d) * 64 + s0;
    bf16x8 o0, o1;
#pragma unroll
    for (int k = 0; k < 8; ++k) { o0[k] = (bf16_t)src[k]; o1[k] = (bf16_t)src[8 + k]; }
    *(bf16x8*)(Ut + base) = o0;
    *(bf16x8*)(Ut + base + 8) = o1;
  }
}

// ---- stage one B chunk: Bt rows [p*256,+256), K-bytes [q*128,+128) -> 32KB ----
// LDS layout [256 rows][128B]; slot Ls (16B) of row r holds global slot Ls^(r&7).
__device__ __forceinline__ void stage_B(char* dst, const char* __restrict__ Bt,
                                        int p, int q, int wave, int t) {
#pragma unroll
  for (int k = 0; k < 4; ++k) {
    int c = k * 512 + t;                       // 2048 chunks of 16B
    int r = c >> 3, Ls = c & 7, gs = Ls ^ (r & 7);
    async16(dst + (k * 512 + wave * 64) * 16,
            Bt + (size_t)(p * 256 + r) * 1024 + q * 128 + gs * 16);
  }
}

// ---- one GEMM phase: 64(slab) x 512 x 512. A resident in ldsX; B via dbuf. ----
// Steps s = p*8+q (p: 256-col half, q: 64-K chunk). Barrier at top completes
// buf[s&1] (staged at s-1); stage s+1 into other buf; compute from buf[s&1].
// Precondition: step (0,0) already staged into ldsB+0 before the call.
__device__ __forceinline__ void gemm_phase(
    const char* ldsX, char* ldsB, const char* __restrict__ Bt,
    int wr, int wc, int lhi, int llo, int wave, int t, floatx4 acc[2][8]) {
  const int rA0 = wr * 32 + llo, rm = rA0 & 7;      // (rA0+16)&7 == rm
  const char* ap0 = ldsX + rA0 * 1024;
  const char* ap1 = ldsX + (rA0 + 16) * 1024;
  const int rB = wc * 64 + llo, rmB = rB & 7;       // (rB+j*16)&7 == rmB
#pragma unroll
  for (int p = 0; p < 2; ++p) {
#pragma unroll 1
    for (int q = 0; q < 8; ++q) {
      const int s = p * 8 + q;
      __syncthreads();                              // buf[s&1] ready (drains vm+lgkm)
      if (p < 1 || q < 7) {
        int np = (q < 7) ? p : p + 1;
        int nq = (q + 1) & 7;
        stage_B(ldsB + ((s + 1) & 1) * 32768, Bt, np, nq, wave, t);
      }
      const char* bbuf = ldsB + (s & 1) * 32768;
#pragma unroll
      for (int kt = 0; kt < 2; ++kt) {
        int ck = (q * 2 + kt) * 4 + lhi;            // A 16B-slot index (0..63)
        int g0 = (ck >> 3) * 128, sq = ck & 7;
        bf16x8 a0 = *(const bf16x8*)(ap0 + g0 + ((sq ^ rm) << 4));
        bf16x8 a1 = *(const bf16x8*)(ap1 + g0 + ((sq ^ rm) << 4));
        int sB = kt * 4 + lhi;                      // B slot within 128B row
        bf16x8 bfr[4];
#pragma unroll
        for (int j = 0; j < 4; ++j)
          bfr[j] = *(const bf16x8*)(bbuf + (rB + j * 16) * 128 + ((sB ^ rmB) << 4));
#pragma unroll
        for (int j = 0; j < 4; ++j) {
          acc[0][p * 4 + j] = MFMA16(a0, bfr[j], acc[0][p * 4 + j], 0, 0, 0);
          acc[1][p * 4 + j] = MFMA16(a1, bfr[j], acc[1][p * 4 + j], 0, 0, 0);
        }
      }
    }
  }
}

// ---------------- K1: gate + GEMM1 -> T(LDS) -> GEMM2 -> epilogue ----------
__global__ __launch_bounds__(512, 2) void fused_kernel(
    const float* __restrict__ x0, const float* __restrict__ x,
    const bf16_t* __restrict__ VCc, const bf16_t* __restrict__ Ut,
    const float* __restrict__ Wg, const float* __restrict__ bg,
    const float* __restrict__ bvec, float* __restrict__ out) {
  __shared__ alignas(16) char lds[133120];
  char*  ldsX = lds;                     // [64][1024B] bf16 swizzled: x, then T
  char*  ldsB = lds + 65536;             // 2 x 32KB B chunks [256 rows][128B]
  float* ldsG = (float*)(lds + 131072);  // [64][8] gates
  const int t = threadIdx.x;
  const int wave = t >> 6, lane = t & 63;
  const int wr = wave >> 2, wc = wave & 3;   // 2m x 4n waves, wave-tile 32x64
  const int lhi = lane >> 4, llo = lane & 15;
  const int m0 = blockIdx.x * 64;

  // ---- stage x slab -> bf16 ldsX (swizzled): 8 chunks of 8 f32 per thread ----
  {
    const float4* xs = (const float4*)(x + (size_t)m0 * 512);
#pragma unroll
    for (int i = 0; i < 8; ++i) {
      int c = i * 512 + t, r = c >> 6, q = c & 63;
      float4 f0 = xs[r * 128 + q * 2];
      float4 f1 = xs[r * 128 + q * 2 + 1];
      bf16x8 v;
      v[0] = (bf16_t)f0.x; v[1] = (bf16_t)f0.y; v[2] = (bf16_t)f0.z; v[3] = (bf16_t)f0.w;
      v[4] = (bf16_t)f1.x; v[5] = (bf16_t)f1.y; v[6] = (bf16_t)f1.z; v[7] = (bf16_t)f1.w;
      int slot = (q & 7) ^ (r & 7);
      *(bf16x8*)(ldsX + r * 1024 + (q >> 3) * 128 + slot * 16) = v;
    }
  }
  // ---- prologue: stage phase-0 step (0,0) into buf0 ----
  stage_B(ldsB, (const char*)VCc, 0, 0, wave, t);

  // ---- gate: wave handles rows wave*8+p; f32 dot + butterfly + softmax ----
#pragma unroll 1
  for (int p = 0; p < 8; ++p) {
    const int rl = wave * 8 + p;
    const float4* xr = (const float4*)(x + (size_t)(m0 + rl) * 512 + lane * 8);
    float4 xa = xr[0], xb = xr[1];
    float z[8];
#pragma unroll
    for (int e = 0; e < 8; ++e) {
      const float4* wp = (const float4*)(Wg + (size_t)e * 512 + lane * 8);
      float4 wa = wp[0], wb = wp[1];
      z[e] = xa.x * wa.x + xa.y * wa.y + xa.z * wa.z + xa.w * wa.w +
             xb.x * wb.x + xb.y * wb.y + xb.z * wb.z + xb.w * wb.w;
    }
#pragma unroll
    for (int e = 0; e < 8; ++e)
#pragma unroll
      for (int off = 32; off > 0; off >>= 1) z[e] += __shfl_xor(z[e], off, 64);
    if (lane == 0) {
      float mx = -1e30f, ssum = 0.f;
#pragma unroll
      for (int e = 0; e < 8; ++e) { z[e] += bg[e]; mx = fmaxf(mx, z[e]); }
#pragma unroll
      for (int e = 0; e < 8; ++e) { z[e] = __expf(z[e] - mx); ssum += z[e]; }
      float inv = 1.f / ssum;
      float4 ga = {z[0] * inv, z[1] * inv, z[2] * inv, z[3] * inv};
      float4 gb = {z[4] * inv, z[5] * inv, z[6] * inv, z[7] * inv};
      *(float4*)(ldsG + rl * 8) = ga;
      *(float4*)(ldsG + rl * 8 + 4) = gb;
    }
  }

  // ---- phase 0: GEMM1 (A = x slab, B = VCc); first barrier inside ----
  floatx4 acc[2][8];
#pragma unroll
  for (int i = 0; i < 2; ++i)
#pragma unroll
    for (int jj = 0; jj < 8; ++jj) acc[i][jj] = (floatx4){0.f, 0.f, 0.f, 0.f};
  gemm_phase(ldsX, ldsB, (const char*)VCc, wr, wc, lhi, llo, wave, t, acc);

  // prefetch phase-1 step (0,0) into buf0 (buf0's readers finished at s=14)
  stage_B(ldsB, (const char*)Ut, 0, 0, wave, t);
  __syncthreads();   // all waves done with phase 0 (ldsX free)

  // ---- T = gate-scaled xvc, written over ldsX (bf16, same swizzle) ----
#pragma unroll
  for (int p = 0; p < 2; ++p) {
    const int e = p * 4 + wc;                      // n>>6, wave-uniform
#pragma unroll
    for (int i = 0; i < 2; ++i)
#pragma unroll
      for (int r = 0; r < 4; ++r) {
        int ml = wr * 32 + i * 16 + lhi * 4 + r;   // C/D: col=lane&15, row=quad*4+reg
        float gv = ldsG[ml * 8 + e];
#pragma unroll
        for (int j = 0; j < 4; ++j) {
          int n = p * 256 + wc * 64 + j * 16 + llo;
          int qc = n >> 3, slot = (qc & 7) ^ (ml & 7);
          *(bf16_t*)(ldsX + ml * 1024 + (qc >> 3) * 128 + slot * 16 + (n & 7) * 2) =
              (bf16_t)(acc[i][p * 4 + j][r] * gv);
        }
      }
  }

  // ---- phase 1: GEMM2 (A = T slab, B = Ut); first barrier syncs T + buf0 ----
#pragma unroll
  for (int i = 0; i < 2; ++i)
#pragma unroll
    for (int jj = 0; jj < 8; ++jj) acc[i][jj] = (floatx4){0.f, 0.f, 0.f, 0.f};
  gemm_phase(ldsX, ldsB, (const char*)Ut, wr, wc, lhi, llo, wave, t, acc);

  // ---- final epilogue: out = x0*gproj + g@b + x*sum(g) ----
#pragma unroll
  for (int p = 0; p < 2; ++p) {
    float bb[4][8];
#pragma unroll
    for (int j = 0; j < 4; ++j) {
      int n = p * 256 + wc * 64 + j * 16 + llo;
#pragma unroll
      for (int e = 0; e < 8; ++e) bb[j][e] = bvec[(size_t)e * 512 + n];
    }
#pragma unroll
    for (int i = 0; i < 2; ++i)
#pragma unroll
      for (int r = 0; r < 4; ++r) {
        int ml = wr * 32 + i * 16 + lhi * 4 + r;
        float4 ga = *(const float4*)(ldsG + ml * 8);
        float4 gb = *(const float4*)(ldsG + ml * 8 + 4);
        float g8[8] = {ga.x, ga.y, ga.z, ga.w, gb.x, gb.y, gb.z, gb.w};
        float gsum = ga.x + ga.y + ga.z + ga.w + gb.x + gb.y + gb.z + gb.w;
        size_t mrow = (size_t)(m0 + ml) * 512;
#pragma unroll
        for (int j = 0; j < 4; ++j) {
          int n = p * 256 + wc * 64 + j * 16 + llo;
          float bias = 0.f;
#pragma unroll
          for (int e = 0; e < 8; ++e) bias += g8[e] * bb[j][e];
          size_t idx = mrow + n;
          out[idx] = x0[idx] * acc[i][p * 4 + j][r] + bias + x[idx] * gsum;
        }
      }
  }
}

// ---------------- launch ----------------------------------------------------
extern "C" void kernel_launch(void* const* d_in, const int* in_sizes, int n_in,
                              void* d_out, int out_size, void* d_ws, size_t ws_size,
                              hipStream_t stream) {
  const float* x0 = (const float*)d_in[0];
  const float* x  = (const float*)d_in[1];
  const float* U  = (const float*)d_in[2];
  const float* V  = (const float*)d_in[3];
  const float* C  = (const float*)d_in[4];
  const float* bv = (const float*)d_in[5];
  const float* Wg = (const float*)d_in[6];
  const float* bg = (const float*)d_in[7];
  float* out = (float*)d_out;

  char* ws = (char*)d_ws;
  bf16_t* VCc = (bf16_t*)(ws);              // 524,288 B
  bf16_t* Ut  = (bf16_t*)(ws + 524288);     // 524,288 B

  prep_kernel<<<128, 256, 0, stream>>>(U, V, C, VCc, Ut);
  fused_kernel<<<256, 512, 0, stream>>>(x0, x, VCc, Ut, Wg, bg, bv, out);
}